// Round 1
// baseline (283.519 us; speedup 1.0000x reference)
//
#include <hip/hip_runtime.h>

#define N_NODES   100000
#define D_DIM     16
#define NFILT     8
#define KOUT      128
#define NNZ_CNT   1600000

#define CBITS     8
#define CROWS     256                                  // rows per coarse bucket
#define NCB       ((N_NODES + CROWS - 1) / CROWS)      // 391 buckets
#define CAP       5120                                 // record slots per bucket (mean 4092, sigma 64)
#define EPB       4096                                 // edges per binA block
#define NBLKA     ((NNZ_CNT + EPB - 1) / EPB)          // 391

// fp32 -> bf16 bits with round-to-nearest-even (same as __float2bfloat16)
__device__ __forceinline__ uint f32_to_bf16_bits(float f) {
    uint u = __float_as_uint(f);
    uint r = (u + 0x7FFFu + ((u >> 16) & 1u)) >> 16;
    return r;
}

// w_wav[n,f] = t^(2^f) - t^(2^(f+1)); fp32 compute, bf16 store (RNE)
__global__ void wav_kernel(const float* __restrict__ eig, ushort* __restrict__ wavb) {
    int n = blockIdx.x * blockDim.x + threadIdx.x;
    if (n >= N_NODES) return;
    float cur = expf(-eig[n]);
    uint pk[4];
#pragma unroll
    for (int h = 0; h < 4; ++h) {
        float nx0 = cur * cur;
        float w0 = cur - nx0;
        float nx1 = nx0 * nx0;
        float w1 = nx0 - nx1;
        cur = nx1;
        pk[h] = f32_to_bf16_bits(w0) | (f32_to_bf16_bits(w1) << 16);
    }
    *(uint4*)(wavb + (size_t)n * NFILT) = make_uint4(pk[0], pk[1], pk[2], pk[3]);
}

// binA: block-local coarse sort into 391 buckets of 256 keys; per-bucket runs
// appended with ONE cursor bump -> block-private contiguous global writes.
// Key-symmetric: pass (rows, cols) for row-binning, (cols, rows) for col-binning.
// Record: x = ((key&255)<<17) | payload, y = bits of v.
__global__ __launch_bounds__(512) void binA_kernel(const int* __restrict__ keys,
                                                   const int* __restrict__ pays,
                                                   const float* __restrict__ v,
                                                   int* __restrict__ gcur,
                                                   int2* __restrict__ regA) {
    __shared__ int cnt[NCB];
    __shared__ int offb[NCB];
    __shared__ int gbase[NCB];
    __shared__ int sc[512];
    __shared__ int2 rec[EPB];
    int tid = threadIdx.x;
    int e0 = blockIdx.x * EPB;
    int nE = NNZ_CNT - e0; if (nE > EPB) nE = EPB;

    for (int i = tid; i < NCB; i += 512) cnt[i] = 0;
    __syncthreads();
    for (int i = tid; i < nE; i += 512)
        atomicAdd(&cnt[keys[e0 + i] >> CBITS], 1);
    __syncthreads();

    // exclusive scan of 391 counts (padded to 512, 1 elem/thread)
    sc[tid] = (tid < NCB) ? cnt[tid] : 0;
    __syncthreads();
    for (int off = 1; off < 512; off <<= 1) {
        int t = (tid >= off) ? sc[tid - off] : 0;
        __syncthreads();
        sc[tid] += t;
        __syncthreads();
    }
    if (tid < NCB) {
        int cv = cnt[tid];
        int st = sc[tid] - cv;
        offb[tid] = st;
        gbase[tid] = cv ? atomicAdd(&gcur[tid], cv) : 0;
        cnt[tid] = st;   // becomes cursor
    }
    __syncthreads();

    for (int i = tid; i < nE; i += 512) {
        int k = keys[e0 + i], p = pays[e0 + i];
        float val = v[e0 + i];
        int b = k >> CBITS;
        int pos = atomicAdd(&cnt[b], 1);
        rec[pos] = make_int2(((k & (CROWS - 1)) << 17) | p, __float_as_int(val));
    }
    __syncthreads();

    // copy runs out: wave per bucket (~10.5 records per run)
    int wv = tid >> 6, lane = tid & 63;
    for (int b = wv; b < NCB; b += 8) {
        int s = offb[b];
        int n = cnt[b] - s;
        size_t dst = (size_t)b * CAP + gbase[b];
        for (int i = lane; i < n; i += 64)
            regA[dst + i] = rec[s + i];
    }
}

// binB: one block per bucket; LDS count+scan over 256 keys; key-sorted records
// written back IN PLACE (block-private window); offs2[key] = {start, end}.
__global__ __launch_bounds__(512) void binB_kernel(const int* __restrict__ gcur,
                                                   int2* __restrict__ regA,
                                                   int2* __restrict__ offs2) {
    __shared__ int2 rec[CAP];
    __shared__ int cnt[CROWS];
    __shared__ int sc[CROWS];
    int tid = threadIdx.x;
    int b = blockIdx.x;
    int nb = gcur[b]; if (nb > CAP) nb = CAP;
    size_t base = (size_t)b * CAP;

    if (tid < CROWS) cnt[tid] = 0;
    __syncthreads();
    for (int i = tid; i < nb; i += 512) {
        int2 r = regA[base + i];
        rec[i] = r;
        atomicAdd(&cnt[r.x >> 17], 1);
    }
    __syncthreads();

    int cv = (tid < CROWS) ? cnt[tid] : 0;
    if (tid < CROWS) sc[tid] = cv;
    __syncthreads();
    for (int off = 1; off < CROWS; off <<= 1) {
        int t = (tid < CROWS && tid >= off) ? sc[tid - off] : 0;
        __syncthreads();
        if (tid < CROWS) sc[tid] += t;
        __syncthreads();
    }
    if (tid < CROWS) {
        int st = sc[tid] - cv;
        int key = b * CROWS + tid;
        if (key < N_NODES)
            offs2[key] = make_int2((int)base + st, (int)base + st + cv);
        cnt[tid] = st;   // becomes cursor
    }
    __syncthreads();

    for (int i = tid; i < nb; i += 512) {
        int2 r = rec[i];
        int p = atomicAdd(&cnt[r.x >> 17], 1);
        regA[base + p] = make_int2(r.x & 0x1FFFF, r.y);
    }
}

// Pass 1 gather (replaces atomic scatter): one wave per column.
// 4 sub-groups of 16 lanes each walk a quarter of the column's edges:
//   acc[d] += v * x[r][d]   (x row read = 64B fully coalesced, record is broadcast)
// then shfl_xor reduce across sub-groups and pack bf16 pairs {d, d+8} into LTxP.
__global__ __launch_bounds__(256) void gather1_kernel(const int2* __restrict__ offs2,
                                                      const int2* __restrict__ ep,
                                                      const float* __restrict__ x,
                                                      uint* __restrict__ LTxP) {
    int wave = (int)(((long long)blockIdx.x * blockDim.x + threadIdx.x) >> 6);
    if (wave >= N_NODES) return;
    int lane = threadIdx.x & 63;
    int c = wave;
    int d = lane & 15;         // feature dim
    int j = lane >> 4;         // sub-group 0..3
    int2 se = offs2[c];
    float acc = 0.f;
    for (int i = se.x + j; i < se.y; i += 4) {
        int2 e = ep[i];
        acc = fmaf(__int_as_float(e.y), x[(size_t)e.x * D_DIM + d], acc);
    }
    // reduce across the 4 sub-groups (lanes d, d+16, d+32, d+48)
    acc += __shfl_xor(acc, 16);
    acc += __shfl_xor(acc, 32);
    // lanes 0..15 hold LTx[c][d]; pack pairs {d, d+8} -> u32 (low=d, high=d+8)
    float hi = __shfl_down(acc, 8);
    if (lane < 8)
        LTxP[(size_t)c * NFILT + lane] = f32_to_bf16_bits(acc) | (f32_to_bf16_bits(hi) << 16);
}

// Pass 2 gather: one wave per row; lane owns outputs (lane) and (lane+64).
// bf16-packed operands: LTxP u32 = {bf16 d, bf16 d+8}, wav bf16.
__global__ __launch_bounds__(256) void gather2_kernel(const int2* __restrict__ offs2,
                                                      const int2* __restrict__ ep,
                                                      const uint* __restrict__ LTxP,
                                                      const ushort* __restrict__ wavb,
                                                      float* __restrict__ out) {
    int wave = (int)(((long long)blockIdx.x * blockDim.x + threadIdx.x) >> 6);
    if (wave >= N_NODES) return;
    int lane = threadIdx.x & 63;
    int r = wave;
    int d0 = lane >> 3;        // pair index 0..7
    int f  = lane & 7;         // 0..7
    int2 se = offs2[r];
    int i = se.x, end = se.y;
    float acc0 = 0.f, acc1 = 0.f;
    for (; i + 4 <= end; i += 4) {
        int2 e0 = ep[i], e1 = ep[i + 1], e2 = ep[i + 2], e3 = ep[i + 3];
        uint l0 = LTxP[e0.x * NFILT + d0];
        uint l1 = LTxP[e1.x * NFILT + d0];
        uint l2 = LTxP[e2.x * NFILT + d0];
        uint l3 = LTxP[e3.x * NFILT + d0];
        uint w0 = wavb[e0.x * NFILT + f];
        uint w1 = wavb[e1.x * NFILT + f];
        uint w2 = wavb[e2.x * NFILT + f];
        uint w3 = wavb[e3.x * NFILT + f];
        float vw0 = __int_as_float(e0.y) * __uint_as_float(w0 << 16);
        float vw1 = __int_as_float(e1.y) * __uint_as_float(w1 << 16);
        float vw2 = __int_as_float(e2.y) * __uint_as_float(w2 << 16);
        float vw3 = __int_as_float(e3.y) * __uint_as_float(w3 << 16);
        acc0 = fmaf(vw0, __uint_as_float(l0 << 16), acc0);
        acc1 = fmaf(vw0, __uint_as_float(l0 & 0xFFFF0000u), acc1);
        acc0 = fmaf(vw1, __uint_as_float(l1 << 16), acc0);
        acc1 = fmaf(vw1, __uint_as_float(l1 & 0xFFFF0000u), acc1);
        acc0 = fmaf(vw2, __uint_as_float(l2 << 16), acc0);
        acc1 = fmaf(vw2, __uint_as_float(l2 & 0xFFFF0000u), acc1);
        acc0 = fmaf(vw3, __uint_as_float(l3 << 16), acc0);
        acc1 = fmaf(vw3, __uint_as_float(l3 & 0xFFFF0000u), acc1);
    }
    for (; i < end; ++i) {
        int2 e = ep[i];
        uint l = LTxP[e.x * NFILT + d0];
        uint w = wavb[e.x * NFILT + f];
        float vw = __int_as_float(e.y) * __uint_as_float(w << 16);
        acc0 = fmaf(vw, __uint_as_float(l << 16), acc0);
        acc1 = fmaf(vw, __uint_as_float(l & 0xFFFF0000u), acc1);
    }
    out[(size_t)r * KOUT + lane]      = acc0;
    out[(size_t)r * KOUT + 64 + lane] = acc1;
}

extern "C" void kernel_launch(void* const* d_in, const int* in_sizes, int n_in,
                              void* d_out, int out_size, void* d_ws, size_t ws_size,
                              hipStream_t stream) {
    const float* x      = (const float*)d_in[0];
    const int*   L_rows = (const int*)  d_in[1];
    const int*   L_cols = (const int*)  d_in[2];
    const float* L_v    = (const float*)d_in[3];
    const float* eig    = (const float*)d_in[4];
    float* out = (float*)d_out;

    // workspace layout (~22 MB), 8B-aligned segments; regA/offs2 reused
    // across the column-binned pass-1 and row-binned pass-2 (stream-ordered).
    uint*   LTxP  = (uint*)d_ws;                              // [N*8]      3.2 MB (bf16 pairs)
    ushort* wavb  = (ushort*)(LTxP + (size_t)N_NODES * NFILT);// [N*8]      1.6 MB (bf16)
    int2*   offs2 = (int2*)(wavb + (size_t)N_NODES * NFILT);  // [N]        0.8 MB
    int2*   regA  = offs2 + N_NODES;                          // [NCB*CAP] 16.0 MB
    int*    gcur  = (int*)(regA + (size_t)NCB * CAP);         // [2*NCB]
    int*    gcurB = gcur + NCB;

    hipMemsetAsync(gcur, 0, (size_t)2 * NCB * sizeof(int), stream);

    wav_kernel<<<(N_NODES + 255) / 256, 256, 0, stream>>>(eig, wavb);

    // Pass 1: bin by COLUMN, then atomic-free gather producing bf16 LTxP directly
    binA_kernel<<<NBLKA, 512, 0, stream>>>(L_cols, L_rows, L_v, gcurB, regA);
    binB_kernel<<<NCB, 512, 0, stream>>>(gcurB, regA, offs2);
    {
        long long threads = (long long)N_NODES * 64;   // one wave per column
        gather1_kernel<<<(int)((threads + 255) / 256), 256, 0, stream>>>(offs2, regA, x, LTxP);
    }

    // Pass 2: bin by ROW (reusing regA/offs2), then gather
    binA_kernel<<<NBLKA, 512, 0, stream>>>(L_rows, L_cols, L_v, gcur, regA);
    binB_kernel<<<NCB, 512, 0, stream>>>(gcur, regA, offs2);
    {
        long long threads = (long long)N_NODES * 64;   // one wave per row
        gather2_kernel<<<(int)((threads + 255) / 256), 256, 0, stream>>>(offs2, regA, LTxP, wavb, out);
    }
}